// Round 1
// baseline (494.574 us; speedup 1.0000x reference)
//
#include <hip/hip_runtime.h>
#include <math.h>

#define EPS 1e-8f

constexpr int B = 64;
constexpr int N = 65536;
constexpr int M = 64;
constexpr int D = 256;
constexpr int A = M + 6; // 70

// ---- workspace layout (in floats) ----
// kn        : [B*M]      at 0
// scal      : [B*8]      at 4096   (beta,g,s0,s1,s2,gamma per b)
// sim       : [B*N]      at 4608
// mb        : [B]        (max of sim per b)
// Zb        : [B]        (softmax denom)
// Sb        : [B]        (sum of wp)
// wpsum_part: [B*16]
// readpart  : [B*64*M]
constexpr size_t OFF_KN   = 0;
constexpr size_t OFF_SCAL = OFF_KN + (size_t)B * M;          // 4096
constexpr size_t OFF_SIM  = OFF_SCAL + (size_t)B * 8;        // 4608
constexpr size_t OFF_MB   = OFF_SIM + (size_t)B * N;
constexpr size_t OFF_ZB   = OFF_MB + B;
constexpr size_t OFF_SB   = OFF_ZB + B;
constexpr size_t OFF_WPS  = OFF_SB + B;
constexpr size_t OFF_RP   = OFF_WPS + (size_t)B * 16;
// total = OFF_RP + B*64*M  ~= 4.46M floats ~= 17.9 MB

__device__ __forceinline__ float softplusf(float x) {
    return (x > 20.0f) ? x : log1pf(expf(x));
}

// K1: a = emb @ W + b ; derive kn, beta, g, s, gamma. One block per b.
__global__ void k1_controller(const float* __restrict__ emb,
                              const float* __restrict__ Wm,
                              const float* __restrict__ bias,
                              float* __restrict__ kn,
                              float* __restrict__ scal) {
    int b = blockIdx.x;
    int t = threadIdx.x; // 256
    __shared__ float se[D];
    __shared__ float sa[A];
    __shared__ float snorm;
    se[t] = emb[(size_t)b * D + t];
    __syncthreads();
    if (t < A) {
        float acc = bias[t];
        for (int d = 0; d < D; ++d) acc += se[d] * Wm[(size_t)d * A + t];
        sa[t] = acc;
    }
    __syncthreads();
    if (t == 0) {
        float s = 0.f;
        for (int j = 0; j < M; ++j) s += sa[j] * sa[j];
        snorm = sqrtf(s) + EPS;
        float beta = softplusf(sa[M]);
        float g = 1.f / (1.f + expf(-sa[M + 1]));
        float s0 = sa[M + 2], s1 = sa[M + 3], s2 = sa[M + 4];
        float mx = fmaxf(s0, fmaxf(s1, s2));
        float e0 = expf(s0 - mx), e1 = expf(s1 - mx), e2 = expf(s2 - mx);
        float Zs = e0 + e1 + e2;
        float gamma = 1.f + softplusf(sa[M + 5]);
        scal[b * 8 + 0] = beta;
        scal[b * 8 + 1] = g;
        scal[b * 8 + 2] = e0 / Zs;
        scal[b * 8 + 3] = e1 / Zs;
        scal[b * 8 + 4] = e2 / Zs;
        scal[b * 8 + 5] = gamma;
    }
    __syncthreads();
    if (t < M) kn[b * M + t] = sa[t] / snorm;
}

// K2: sim[b,n] = dot(kn[b], mem[b,n,:]) / (||mem[b,n,:]|| + EPS)
// 16 lanes per row, float4 per lane. Block handles 1024 rows.
__global__ void k2_sim(const float* __restrict__ mem,
                       const float* __restrict__ kn,
                       float* __restrict__ sim) {
    const int ROWS = 1024;
    int b = blockIdx.y;
    int base = blockIdx.x * ROWS;
    int t = threadIdx.x; // 256
    int gid = t >> 4, q = t & 15;
    const float4 knq = reinterpret_cast<const float4*>(kn + (size_t)b * M)[q];
    const float4* mrow = reinterpret_cast<const float4*>(mem + (size_t)b * N * M);
    float* sb = sim + (size_t)b * N;
    for (int r = gid; r < ROWS; r += 16) {
        int n = base + r;
        float4 v = mrow[(size_t)n * 16 + q];
        float dot = v.x * knq.x + v.y * knq.y + v.z * knq.z + v.w * knq.w;
        float nrm = v.x * v.x + v.y * v.y + v.z * v.z + v.w * v.w;
        #pragma unroll
        for (int msk = 8; msk >= 1; msk >>= 1) {
            dot += __shfl_xor(dot, msk);
            nrm += __shfl_xor(nrm, msk);
        }
        if (q == 0) sb[n] = dot / (sqrtf(nrm) + EPS);
    }
}

// K3: per-b max(sim) and Z = sum exp(beta*(sim-max)). One 1024-thread block per b.
__global__ void k3_stats(const float* __restrict__ sim,
                         const float* __restrict__ scal,
                         float* __restrict__ mb,
                         float* __restrict__ Zb) {
    int b = blockIdx.x;
    int t = threadIdx.x; // 1024
    const float* sb = sim + (size_t)b * N;
    __shared__ float red[1024];
    float mx = -INFINITY;
    for (int n = t; n < N; n += 1024) mx = fmaxf(mx, sb[n]);
    red[t] = mx;
    __syncthreads();
    for (int k = 512; k >= 1; k >>= 1) {
        if (t < k) red[t] = fmaxf(red[t], red[t + k]);
        __syncthreads();
    }
    float m = red[0];
    float beta = scal[b * 8];
    __syncthreads();
    float sum = 0.f;
    for (int n = t; n < N; n += 1024) sum += expf(beta * (sb[n] - m));
    red[t] = sum;
    __syncthreads();
    for (int k = 512; k >= 1; k >>= 1) {
        if (t < k) red[t] += red[t + k];
        __syncthreads();
    }
    if (t == 0) { mb[b] = m; Zb[b] = red[0]; }
}

// K4: wp = (s0*wg[n-1] + s1*wg[n] + s2*wg[n+1])^gamma, written to w-region of d_out.
// Block-partial sums of wp -> wpsum_part. Block covers 4096 consecutive n.
__global__ void k4_wp(const float* __restrict__ sim,
                      const float* __restrict__ wprev,
                      const float* __restrict__ scal,
                      const float* __restrict__ mb,
                      const float* __restrict__ Zb,
                      float* __restrict__ wout,
                      float* __restrict__ wpsum_part) {
    int b = blockIdx.y;
    int base = blockIdx.x * 4096;
    int t = threadIdx.x; // 256
    float beta = scal[b * 8 + 0];
    float g    = scal[b * 8 + 1];
    float s0   = scal[b * 8 + 2];
    float s1   = scal[b * 8 + 3];
    float s2   = scal[b * 8 + 4];
    float gam  = scal[b * 8 + 5];
    float m = mb[b];
    float invZ = 1.f / Zb[b];
    const float* sb = sim + (size_t)b * N;
    const float* wpv = wprev + (size_t)b * N;
    float* wo = wout + (size_t)b * N;
    float lsum = 0.f;
    for (int i = 0; i < 16; ++i) {
        int n = base + i * 256 + t;
        int nm = (n - 1 + N) & (N - 1);
        int np = (n + 1) & (N - 1);
        float wgm = g * expf(beta * (sb[nm] - m)) * invZ + (1.f - g) * wpv[nm];
        float wgc = g * expf(beta * (sb[n]  - m)) * invZ + (1.f - g) * wpv[n];
        float wgp = g * expf(beta * (sb[np] - m)) * invZ + (1.f - g) * wpv[np];
        float wt = s0 * wgm + s1 * wgc + s2 * wgp;
        float wp = powf(wt, gam);
        wo[n] = wp;
        lsum += wp;
    }
    __shared__ float red[256];
    red[t] = lsum;
    __syncthreads();
    for (int k = 128; k >= 1; k >>= 1) {
        if (t < k) red[t] += red[t + k];
        __syncthreads();
    }
    if (t == 0) wpsum_part[b * 16 + blockIdx.x] = red[0];
}

// K4b: Sb = sum of 16 partials per b. One block, 64 threads.
__global__ void k4b_reduce(const float* __restrict__ wpsum_part,
                           float* __restrict__ Sb) {
    int b = threadIdx.x;
    float s = 0.f;
    for (int i = 0; i < 16; ++i) s += wpsum_part[b * 16 + i];
    Sb[b] = s;
}

// K5: read partials = sum_n (wp[n]*invS) * mem[b,n,:]; also scales w in place.
// Same access structure as K2. Block handles 1024 rows.
__global__ void k5_read(const float* __restrict__ mem,
                        float* __restrict__ wout,
                        const float* __restrict__ Sb,
                        float* __restrict__ readpart) {
    const int ROWS = 1024;
    int b = blockIdx.y;
    int base = blockIdx.x * ROWS;
    int t = threadIdx.x; // 256
    int gid = t >> 4, q = t & 15;
    float invS = 1.f / (Sb[b] + EPS);
    const float4* mrow = reinterpret_cast<const float4*>(mem + (size_t)b * N * M);
    float* wb = wout + (size_t)b * N;
    float4 acc = make_float4(0.f, 0.f, 0.f, 0.f);
    for (int r = gid; r < ROWS; r += 16) {
        int n = base + r;
        float wv = wb[n] * invS;
        float4 v = mrow[(size_t)n * 16 + q];
        acc.x += wv * v.x;
        acc.y += wv * v.y;
        acc.z += wv * v.z;
        acc.w += wv * v.w;
    }
    __shared__ float sacc[16][64];
    sacc[gid][q * 4 + 0] = acc.x;
    sacc[gid][q * 4 + 1] = acc.y;
    sacc[gid][q * 4 + 2] = acc.z;
    sacc[gid][q * 4 + 3] = acc.w;
    __syncthreads();
    // scale w in place (coalesced); all reads of wb done above (sync'd)
    for (int i = 0; i < 4; ++i) {
        int n = base + i * 256 + t;
        wb[n] = wb[n] * invS;
    }
    if (t < 64) {
        float s = 0.f;
        for (int g2 = 0; g2 < 16; ++g2) s += sacc[g2][t];
        readpart[((size_t)b * 64 + blockIdx.x) * 64 + t] = s;
    }
}

// K6: read[b,m] = sum over 64 block-partials.
__global__ void k6_read_reduce(const float* __restrict__ readpart,
                               float* __restrict__ readout) {
    int b = blockIdx.x;
    int m = threadIdx.x; // 64
    float s = 0.f;
    for (int kb = 0; kb < 64; ++kb) s += readpart[((size_t)b * 64 + kb) * 64 + m];
    readout[b * 64 + m] = s;
}

extern "C" void kernel_launch(void* const* d_in, const int* in_sizes, int n_in,
                              void* d_out, int out_size, void* d_ws, size_t ws_size,
                              hipStream_t stream) {
    const float* emb   = (const float*)d_in[0];
    const float* wprev = (const float*)d_in[1];
    const float* mem   = (const float*)d_in[2];
    const float* Wm    = (const float*)d_in[3];
    const float* bias  = (const float*)d_in[4];

    float* out = (float*)d_out;
    float* readout = out;                 // [B, M]
    float* wout    = out + (size_t)B * M; // [B, N]

    float* ws = (float*)d_ws;
    float* kn   = ws + OFF_KN;
    float* scal = ws + OFF_SCAL;
    float* sim  = ws + OFF_SIM;
    float* mb   = ws + OFF_MB;
    float* Zb   = ws + OFF_ZB;
    float* Sb   = ws + OFF_SB;
    float* wps  = ws + OFF_WPS;
    float* rp   = ws + OFF_RP;

    k1_controller<<<dim3(B), dim3(256), 0, stream>>>(emb, Wm, bias, kn, scal);
    k2_sim<<<dim3(N / 1024, B), dim3(256), 0, stream>>>(mem, kn, sim);
    k3_stats<<<dim3(B), dim3(1024), 0, stream>>>(sim, scal, mb, Zb);
    k4_wp<<<dim3(N / 4096, B), dim3(256), 0, stream>>>(sim, wprev, scal, mb, Zb, wout, wps);
    k4b_reduce<<<dim3(1), dim3(B), 0, stream>>>(wps, Sb);
    k5_read<<<dim3(N / 1024, B), dim3(256), 0, stream>>>(mem, wout, Sb, rp);
    k6_read_reduce<<<dim3(B), dim3(64), 0, stream>>>(rp, readout);
}

// Round 2
// 457.720 us; speedup vs baseline: 1.0805x; 1.0805x over previous
//
#include <hip/hip_runtime.h>
#include <math.h>

#define EPS 1e-8f

constexpr int B = 64;
constexpr int N = 65536;
constexpr int M = 64;
constexpr int D = 256;
constexpr int A = M + 6; // 70

// ---- workspace layout (in floats) ----
constexpr size_t OFF_KN   = 0;                               // [B*M]
constexpr size_t OFF_SCAL = OFF_KN + (size_t)B * M;          // [B*8]
constexpr size_t OFF_E    = OFF_SCAL + (size_t)B * 8;        // [B*N]  e = exp(beta*sim)
constexpr size_t OFF_ZP   = OFF_E + (size_t)B * N;           // [B*64] Z partials
constexpr size_t OFF_SP   = OFF_ZP + (size_t)B * 64;         // [B*16] wp-sum partials
constexpr size_t OFF_RP   = OFF_SP + (size_t)B * 16;         // [B*64*M] read partials
// total ~ 4.47M floats ~ 17.9 MB

__device__ __forceinline__ float softplusf(float x) {
    return (x > 20.0f) ? x : log1pf(expf(x));
}

// K1: a = emb @ W + b ; derive kn, beta, g, s, gamma. One block per b.
__global__ void k1_controller(const float* __restrict__ emb,
                              const float* __restrict__ Wm,
                              const float* __restrict__ bias,
                              float* __restrict__ kn,
                              float* __restrict__ scal) {
    int b = blockIdx.x;
    int t = threadIdx.x; // 256
    __shared__ float se[D];
    __shared__ float sa[A];
    __shared__ float snorm;
    se[t] = emb[(size_t)b * D + t];
    __syncthreads();
    if (t < A) {
        float acc = bias[t];
        for (int d = 0; d < D; ++d) acc += se[d] * Wm[(size_t)d * A + t];
        sa[t] = acc;
    }
    __syncthreads();
    if (t == 0) {
        float s = 0.f;
        for (int j = 0; j < M; ++j) s += sa[j] * sa[j];
        snorm = sqrtf(s) + EPS;
        float beta = softplusf(sa[M]);
        float g = 1.f / (1.f + expf(-sa[M + 1]));
        float s0 = sa[M + 2], s1 = sa[M + 3], s2 = sa[M + 4];
        float mx = fmaxf(s0, fmaxf(s1, s2));
        float e0 = expf(s0 - mx), e1 = expf(s1 - mx), e2 = expf(s2 - mx);
        float Zs = e0 + e1 + e2;
        float gamma = 1.f + softplusf(sa[M + 5]);
        scal[b * 8 + 0] = beta;
        scal[b * 8 + 1] = g;
        scal[b * 8 + 2] = e0 / Zs;
        scal[b * 8 + 3] = e1 / Zs;
        scal[b * 8 + 4] = e2 / Zs;
        scal[b * 8 + 5] = gamma;
    }
    __syncthreads();
    if (t < M) kn[b * M + t] = sa[t] / snorm;
}

// K2: e[b,n] = exp(beta * dot(kn, mem_row)/(||mem_row||+EPS)); block partial sums -> zpart.
// |beta*sim| <= beta <= ~3.5 so no max-subtraction needed (pure rounding diff vs ref).
__global__ void k2_sim(const float* __restrict__ mem,
                       const float* __restrict__ kn,
                       const float* __restrict__ scal,
                       float* __restrict__ e,
                       float* __restrict__ zpart) {
    const int ROWS = 1024;
    int b = blockIdx.y;
    int base = blockIdx.x * ROWS;
    int t = threadIdx.x; // 256
    int gid = t >> 4, q = t & 15;
    float beta = scal[b * 8 + 0];
    const float4 knq = reinterpret_cast<const float4*>(kn + (size_t)b * M)[q];
    const float4* mrow = reinterpret_cast<const float4*>(mem + (size_t)b * N * M);
    float* eb = e + (size_t)b * N;
    float lsum = 0.f;
    #pragma unroll 4
    for (int r = gid; r < ROWS; r += 16) {
        int n = base + r;
        float4 v = mrow[(size_t)n * 16 + q];
        float dot = v.x * knq.x + v.y * knq.y + v.z * knq.z + v.w * knq.w;
        float nrm = v.x * v.x + v.y * v.y + v.z * v.z + v.w * v.w;
        #pragma unroll
        for (int msk = 8; msk >= 1; msk >>= 1) {
            dot += __shfl_xor(dot, msk);
            nrm += __shfl_xor(nrm, msk);
        }
        float ev = expf(beta * (dot / (sqrtf(nrm) + EPS)));
        if (q == 0) { eb[n] = ev; lsum += ev; }
    }
    __shared__ float red[16];
    if (q == 0) red[gid] = lsum;
    __syncthreads();
    if (t == 0) {
        float s = 0.f;
        #pragma unroll
        for (int i = 0; i < 16; ++i) s += red[i];
        zpart[b * 64 + blockIdx.x] = s;
    }
}

// K4: wg = (g/Z)*e + (1-g)*wprev ; wt = 3-pt circular stencil ; wp = wt^gamma -> wout.
// Z computed inline from 64 partials (uniform). Vectorized float4, 4 n per thread per iter.
__global__ void k4_wp(const float* __restrict__ e,
                      const float* __restrict__ wprev,
                      const float* __restrict__ scal,
                      const float* __restrict__ zpart,
                      float* __restrict__ wout,
                      float* __restrict__ spart) {
    int b = blockIdx.y;
    int bx = blockIdx.x; // 16
    int t = threadIdx.x; // 256
    float Z = 0.f;
    const float* zp = zpart + b * 64;
    #pragma unroll
    for (int i = 0; i < 64; ++i) Z += zp[i];
    float g   = scal[b * 8 + 1];
    float s0  = scal[b * 8 + 2];
    float s1  = scal[b * 8 + 3];
    float s2  = scal[b * 8 + 4];
    float gam = scal[b * 8 + 5];
    float c1 = g / Z;
    float c2 = 1.f - g;
    const float* eb = e + (size_t)b * N;
    const float* wb = wprev + (size_t)b * N;
    float* wo = wout + (size_t)b * N;
    float lsum = 0.f;
    #pragma unroll
    for (int i = 0; i < 4; ++i) {
        int n0 = bx * 4096 + (i * 256 + t) * 4;
        float4 e4 = *reinterpret_cast<const float4*>(eb + n0);
        float4 w4 = *reinterpret_cast<const float4*>(wb + n0);
        int nm = (n0 - 1) & (N - 1);
        int np = (n0 + 4) & (N - 1);
        float em = eb[nm], ep = eb[np];
        float wm = wb[nm], wp5 = wb[np];
        float wgm = c1 * em   + c2 * wm;
        float wg0 = c1 * e4.x + c2 * w4.x;
        float wg1 = c1 * e4.y + c2 * w4.y;
        float wg2 = c1 * e4.z + c2 * w4.z;
        float wg3 = c1 * e4.w + c2 * w4.w;
        float wg4 = c1 * ep   + c2 * wp5;
        float p0 = powf(s0 * wgm + s1 * wg0 + s2 * wg1, gam);
        float p1 = powf(s0 * wg0 + s1 * wg1 + s2 * wg2, gam);
        float p2 = powf(s0 * wg1 + s1 * wg2 + s2 * wg3, gam);
        float p3 = powf(s0 * wg2 + s1 * wg3 + s2 * wg4, gam);
        lsum += (p0 + p1) + (p2 + p3);
        *reinterpret_cast<float4*>(wo + n0) = make_float4(p0, p1, p2, p3);
    }
    __shared__ float red[256];
    red[t] = lsum;
    __syncthreads();
    for (int k = 128; k >= 1; k >>= 1) {
        if (t < k) red[t] += red[t + k];
        __syncthreads();
    }
    if (t == 0) spart[b * 16 + bx] = red[0];
}

// K5: read partials = sum_n (wp[n]*invS) * mem[b,n,:]; scales w in place.
// S computed inline from 16 partials (uniform).
__global__ void k5_read(const float* __restrict__ mem,
                        float* __restrict__ wout,
                        const float* __restrict__ spart,
                        float* __restrict__ readpart) {
    const int ROWS = 1024;
    int b = blockIdx.y;
    int base = blockIdx.x * ROWS;
    int t = threadIdx.x; // 256
    int gid = t >> 4, q = t & 15;
    float S = 0.f;
    const float* sp = spart + b * 16;
    #pragma unroll
    for (int i = 0; i < 16; ++i) S += sp[i];
    float invS = 1.f / (S + EPS);
    const float4* mrow = reinterpret_cast<const float4*>(mem + (size_t)b * N * M);
    float* wb = wout + (size_t)b * N;
    float4 acc = make_float4(0.f, 0.f, 0.f, 0.f);
    #pragma unroll 4
    for (int r = gid; r < ROWS; r += 16) {
        int n = base + r;
        float wv = wb[n] * invS;
        float4 v = mrow[(size_t)n * 16 + q];
        acc.x += wv * v.x;
        acc.y += wv * v.y;
        acc.z += wv * v.z;
        acc.w += wv * v.w;
    }
    __shared__ float sacc[16][64];
    sacc[gid][q * 4 + 0] = acc.x;
    sacc[gid][q * 4 + 1] = acc.y;
    sacc[gid][q * 4 + 2] = acc.z;
    sacc[gid][q * 4 + 3] = acc.w;
    __syncthreads();
    // scale w in place (coalesced); all reads of wb done above (sync'd)
    #pragma unroll
    for (int i = 0; i < 4; ++i) {
        int n = base + i * 256 + t;
        wb[n] = wb[n] * invS;
    }
    if (t < 64) {
        float s = 0.f;
        #pragma unroll
        for (int g2 = 0; g2 < 16; ++g2) s += sacc[g2][t];
        readpart[((size_t)b * 64 + blockIdx.x) * 64 + t] = s;
    }
}

// K6: read[b,m] = sum over 64 block-partials.
__global__ void k6_read_reduce(const float* __restrict__ readpart,
                               float* __restrict__ readout) {
    int b = blockIdx.x;
    int m = threadIdx.x; // 64
    float s = 0.f;
    #pragma unroll
    for (int kb = 0; kb < 64; ++kb) s += readpart[((size_t)b * 64 + kb) * 64 + m];
    readout[b * 64 + m] = s;
}

extern "C" void kernel_launch(void* const* d_in, const int* in_sizes, int n_in,
                              void* d_out, int out_size, void* d_ws, size_t ws_size,
                              hipStream_t stream) {
    const float* emb   = (const float*)d_in[0];
    const float* wprev = (const float*)d_in[1];
    const float* mem   = (const float*)d_in[2];
    const float* Wm    = (const float*)d_in[3];
    const float* bias  = (const float*)d_in[4];

    float* out = (float*)d_out;
    float* readout = out;                 // [B, M]
    float* wout    = out + (size_t)B * M; // [B, N]

    float* ws = (float*)d_ws;
    float* kn   = ws + OFF_KN;
    float* scal = ws + OFF_SCAL;
    float* e    = ws + OFF_E;
    float* zp   = ws + OFF_ZP;
    float* sp   = ws + OFF_SP;
    float* rp   = ws + OFF_RP;

    k1_controller<<<dim3(B), dim3(256), 0, stream>>>(emb, Wm, bias, kn, scal);
    k2_sim<<<dim3(N / 1024, B), dim3(256), 0, stream>>>(mem, kn, scal, e, zp);
    k4_wp<<<dim3(N / 4096, B), dim3(256), 0, stream>>>(e, wprev, scal, zp, wout, sp);
    k5_read<<<dim3(N / 1024, B), dim3(256), 0, stream>>>(mem, wout, sp, rp);
    k6_read_reduce<<<dim3(B), dim3(64), 0, stream>>>(rp, readout);
}